// Round 6
// baseline (341.226 us; speedup 1.0000x reference)
//
#include <hip/hip_runtime.h>
#include <hip/hip_bf16.h>

// VirtualTextureModule: trilinear mip-mapped texture sampling.
// data [1,4096,4096,3] f32, texc [1,1024,1024,2] f32, texc_deriv [1,1024,1024,4] f32
// out  [1,1024,1024,3] f32
//
// R10 design (dense + convoy-free staging; T3/T4 counted-vmcnt pipeline):
//  - mip_l2: persistent, 256 blocks (1/CU), LDS = 2 x 48 KB double buffer.
//    Group = 4 raw rows x 1024 cols (one L2 row-segment, 48 KB). Per group:
//    issue 12 dense 1-KB global_load_lds for group n+1, s_waitcnt vmcnt(12)
//    (group n complete, n+1 stays IN FLIGHT across the raw s_barrier — never
//    vmcnt(0) in the loop), compute 1 L2 texel/thread, barrier, repeat.
//    LDS XOR-involution slot = u ^ ((u>>3)&7) kills the stride-48 8-way bank
//    conflict: linear gload_lds dest + inverse-swizzled global source (rule:
//    both-sides-or-neither) — source permutes only within 128-B lines, so
//    per-instruction density is preserved.
//  - mip_rest: 1024 blocks; L3..L6 from the fp32 L2 copy at FOFF (unchanged).
//  - sampler: linear level layout, fused dual-level fast path (unchanged).

#define OUT_N (1024 * 1024)

__device__ __forceinline__ unsigned mip_off_b(int lvl) {
    return (67108864u - (67108864u >> (2 * lvl - 2))) / 3u;
}
#define OFF2 16777216u
#define OFF3 20971520u
#define OFF4 22020096u
#define OFF5 22282240u
#define OFF6 22347776u
#define FOFF 25165824u   // fp32 float4 L2 copy: [24 MB, 40 MB)

__device__ __forceinline__ unsigned pack10(float r, float g, float b) {
    unsigned ur = __float2uint_rn(r * 1023.0f);
    unsigned ug = __float2uint_rn(g * 1023.0f);
    unsigned ub = __float2uint_rn(b * 1023.0f);
    return ur | (ug << 10) | (ub << 20);
}

__device__ __forceinline__ void dec_acc(unsigned q, float w, float& r, float& g, float& b) {
    const float s = 1.0f / 1023.0f;
    r = fmaf((float)(q & 1023u) * s, w, r);
    g = fmaf((float)((q >> 10) & 1023u) * s, w, g);
    b = fmaf((float)((q >> 20) & 1023u) * s, w, b);
}

__device__ __forceinline__ float4 dec4(unsigned q) {
    const float s = 1.0f / 1023.0f;
    return float4{(float)(q & 1023u) * s, (float)((q >> 10) & 1023u) * s,
                  (float)((q >> 20) & 1023u) * s, 0.0f};
}

__device__ __forceinline__ float4 avg4(float4 a, float4 b, float4 c, float4 d) {
    return float4{(a.x + b.x + c.x + d.x) * 0.25f,
                  (a.y + b.y + c.y + d.y) * 0.25f,
                  (a.z + b.z + c.z + d.z) * 0.25f, 0.0f};
}

// ---------------- kernel A: L2 build (pipelined dense streaming) --------
// 256 blocks x 256 threads; block b owns groups G = b*16 + j (j=0..15).
// G -> l2row = G>>2, seg = G&3. Group bytes: raw rows 4*l2row..+3,
// cols seg*1024..+1024 (each row-chunk 12 KB, 16-B aligned).
__global__ __launch_bounds__(256) void mip_l2(const float* __restrict__ data,
                                              char* __restrict__ wsb) {
    __shared__ float4 lds4[2][3072];          // 2 x 48 KB double buffer
    const int t = threadIdx.x;
    const unsigned b = blockIdx.x;            // 0..255
    // inverse-swizzled source unit for linear LDS slot (low-3-bit involution)
    const unsigned xm = (unsigned)t ^ (((unsigned)t >> 3) & 7u);

#define STAGE(J, BUF)                                                            \
    {                                                                            \
        unsigned G_ = (b << 4) + (unsigned)(J);                                  \
        const char* gb_ = (const char*)data + (size_t)(G_ >> 2) * 196608 +       \
                          (size_t)(G_ & 3) * 12288;                              \
        char* lb_ = (char*)lds4[BUF];                                            \
        _Pragma("unroll")                                                        \
        for (int r_ = 0; r_ < 4; ++r_) {                                         \
            _Pragma("unroll")                                                    \
            for (int k_ = 0; k_ < 3; ++k_) {                                     \
                __builtin_amdgcn_global_load_lds(                                \
                    (const __attribute__((address_space(1))) unsigned int*)      \
                        (gb_ + (size_t)r_ * 49152 + (size_t)k_ * 4096 +          \
                         (size_t)xm * 16),                                       \
                    (__attribute__((address_space(3))) unsigned int*)            \
                        (lb_ + ((size_t)r_ * 768 + (size_t)k_ * 256 +            \
                                (size_t)t) * 16),                                \
                    16, 0, 0);                                                   \
            }                                                                    \
        }                                                                        \
    }

    STAGE(0, 0)
    for (int g = 0; g < 16; ++g) {
        if (g < 15) {
            STAGE(g + 1, (g + 1) & 1)
            // wait group g's 12 loads (and older stores); keep g+1's 12 in flight
            asm volatile("s_waitcnt vmcnt(12)" ::: "memory");
        } else {
            asm volatile("s_waitcnt vmcnt(0)" ::: "memory");
        }
        __builtin_amdgcn_sched_barrier(0);
        __builtin_amdgcn_s_barrier();
        __builtin_amdgcn_sched_barrier(0);

        // compute one L2 texel from buffer g&1 (swizzled reads, conflict-free)
        const char* lb = (const char*)lds4[g & 1];
        float rr = 0.0f, gg = 0.0f, bb = 0.0f;
#pragma unroll
        for (int r = 0; r < 4; ++r) {
            unsigned u0 = (unsigned)(r * 768 + 3 * t);
            unsigned s0 = u0 ^ ((u0 >> 3) & 7u);
            unsigned u1 = u0 + 1, u2 = u0 + 2;
            unsigned s1 = u1 ^ ((u1 >> 3) & 7u);
            unsigned s2 = u2 ^ ((u2 >> 3) & 7u);
            float4 A  = *(const float4*)(lb + (size_t)s0 * 16);
            float4 Bv = *(const float4*)(lb + (size_t)s1 * 16);
            float4 Cv = *(const float4*)(lb + (size_t)s2 * 16);
            // texels: (A.x,A.y,A.z)(A.w,Bv.x,Bv.y)(Bv.z,Bv.w,Cv.x)(Cv.y,Cv.z,Cv.w)
            rr += A.x + A.w + Bv.z + Cv.y;
            gg += A.y + Bv.x + Bv.w + Cv.z;
            bb += A.z + Bv.y + Cv.x + Cv.w;
        }
        const float sc = 1.0f / 16.0f;
        rr *= sc; gg *= sc; bb *= sc;

        unsigned G = (b << 4) + (unsigned)g;
        size_t idx = ((size_t)(G >> 2) << 10) + ((size_t)(G & 3) << 8) + (size_t)t;
        *(unsigned*)(wsb + OFF2 + idx * 4) = pack10(rr, gg, bb);        // sampler
        *(float4*)(wsb + FOFF + idx * 16) = float4{rr, gg, bb, 0.0f};   // ladder

        __builtin_amdgcn_s_barrier();   // all reads of buf g&1 done before overwrite
    }
#undef STAGE
}

// ---------------- kernel B: L3..L6 from fp32 L2 copy ----------------
// Block = 32x32 L2 region (16x16 L3). 1024 blocks.
__global__ __launch_bounds__(256) void mip_rest(char* __restrict__ wsb) {
    __shared__ float4 s3[16][17];
    __shared__ float4 s4[8][9];
    __shared__ float4 s5[4][5];
    const int t = threadIdx.x;
    const unsigned bby = blockIdx.x >> 5;   // 0..31
    const unsigned bbx = blockIdx.x & 31;

    {   // L3: one texel per thread
        int tx = t & 15, ty = t >> 4;
        unsigned R3 = (bby << 4) + ty;      // 0..511
        unsigned C3 = (bbx << 4) + tx;
        const char* F = wsb + FOFF;
        const float4* p0 = (const float4*)(F + ((((size_t)R3 * 2) << 10) + (size_t)C3 * 2) * 16);
        const float4* p1 = (const float4*)(F + ((((size_t)R3 * 2 + 1) << 10) + (size_t)C3 * 2) * 16);
        float4 v = avg4(p0[0], p0[1], p1[0], p1[1]);
        s3[ty][tx] = v;
        *(unsigned*)(wsb + OFF3 + (((size_t)R3 << 9) + C3) * 4) = pack10(v.x, v.y, v.z);
    }
    __syncthreads();

    if (t < 64) {   // L4
        int tx = t & 7, ty = t >> 3;
        float4 v = avg4(s3[2 * ty][2 * tx], s3[2 * ty][2 * tx + 1],
                        s3[2 * ty + 1][2 * tx], s3[2 * ty + 1][2 * tx + 1]);
        s4[ty][tx] = v;
        unsigned R4 = (bby << 3) + ty, C4 = (bbx << 3) + tx;   // 0..255
        *(unsigned*)(wsb + OFF4 + (((size_t)R4 << 8) + C4) * 4) = pack10(v.x, v.y, v.z);
    }
    __syncthreads();

    if (t < 16) {   // L5
        int tx = t & 3, ty = t >> 2;
        float4 v = avg4(s4[2 * ty][2 * tx], s4[2 * ty][2 * tx + 1],
                        s4[2 * ty + 1][2 * tx], s4[2 * ty + 1][2 * tx + 1]);
        s5[ty][tx] = v;
        unsigned R5 = (bby << 2) + ty, C5 = (bbx << 2) + tx;   // 0..127
        *(unsigned*)(wsb + OFF5 + (((size_t)R5 << 7) + C5) * 4) = pack10(v.x, v.y, v.z);
    }
    __syncthreads();

    if (t < 4) {    // L6
        int tx = t & 1, ty = t >> 1;
        float4 v = avg4(s5[2 * ty][2 * tx], s5[2 * ty][2 * tx + 1],
                        s5[2 * ty + 1][2 * tx], s5[2 * ty + 1][2 * tx + 1]);
        unsigned R6r = (bby << 1) + ty, C6 = (bbx << 1) + tx;  // 0..63
        *(unsigned*)(wsb + OFF6 + (((size_t)R6r << 6) + C6) * 4) = pack10(v.x, v.y, v.z);
    }
}

// ---------------- sampling (linear level layout) ----------------
__device__ __forceinline__ void tap_off(int lvl, float u, float v,
                                        unsigned& o00, unsigned& o01,
                                        unsigned& o10, unsigned& o11,
                                        float& fx, float& fy) {
    int size = 4096 >> lvl;
    float fs = (float)size;
    float x = fmaf(u, fs, -0.5f);
    float y = fmaf(v, fs, -0.5f);
    float x0f = floorf(x);
    float y0f = floorf(y);
    fx = x - x0f;
    fy = y - y0f;
    int m = size - 1;
    unsigned x0 = (unsigned)(((int)x0f) & m);
    unsigned y0 = (unsigned)(((int)y0f) & m);
    unsigned x1 = (x0 + 1) & (unsigned)m;
    unsigned y1 = (y0 + 1) & (unsigned)m;
    int sh = 12 - lvl;                       // y*size == y << sh
    unsigned r0 = y0 << sh, r1 = y1 << sh;
    o00 = (r0 + x0) << 2;
    o01 = (r0 + x1) << 2;
    o10 = (r1 + x0) << 2;
    o11 = (r1 + x1) << 2;
}

__device__ __forceinline__ void sample_packed(const char* __restrict__ wsb, int lvl,
                                              float u, float v, float wgt,
                                              float& r, float& g, float& b) {
    unsigned o00, o01, o10, o11;
    float fx, fy;
    tap_off(lvl, u, v, o00, o01, o10, o11, fx, fy);
    const char* B = wsb + mip_off_b(lvl);
    unsigned q00 = *(const unsigned*)(B + o00);
    unsigned q01 = *(const unsigned*)(B + o01);
    unsigned q10 = *(const unsigned*)(B + o10);
    unsigned q11 = *(const unsigned*)(B + o11);
    dec_acc(q00, (1.0f - fx) * (1.0f - fy) * wgt, r, g, b);
    dec_acc(q01, fx * (1.0f - fy) * wgt, r, g, b);
    dec_acc(q10, (1.0f - fx) * fy * wgt, r, g, b);
    dec_acc(q11, fx * fy * wgt, r, g, b);
}

// Rare path (lod < 2, ~1.3%): levels 0..1 on the fly from fp32 data.
__device__ void sample_fine(const float* __restrict__ data, int lvl,
                            float u, float v, float wgt,
                            float& r, float& g, float& b) {
    int size = 4096 >> lvl;
    float fs = (float)size;
    float x = u * fs - 0.5f;
    float y = v * fs - 0.5f;
    float x0f = floorf(x);
    float y0f = floorf(y);
    float fx = x - x0f;
    float fy = y - y0f;
    int m = size - 1;
    int x0 = ((int)x0f) & m;
    int y0 = ((int)y0f) & m;
    int x1 = (x0 + 1) & m;
    int y1 = (y0 + 1) & m;
    int k = 1 << lvl;
    float inv = wgt / (float)(k * k);
    float ww[2][2] = {{(1.0f - fx) * (1.0f - fy) * inv, fx * (1.0f - fy) * inv},
                      {(1.0f - fx) * fy * inv, fx * fy * inv}};
    int xs[2] = {x0 << lvl, x1 << lvl};
    int ys[2] = {y0 << lvl, y1 << lvl};
    for (int ty = 0; ty < 2; ++ty)
        for (int tx = 0; tx < 2; ++tx) {
            float tr = 0.0f, tg = 0.0f, tb = 0.0f;
            for (int dy = 0; dy < k; ++dy)
                for (int dx = 0; dx < k; ++dx) {
                    const float* p = data + ((size_t)(ys[ty] + dy) * 4096 + xs[tx] + dx) * 3;
                    tr += p[0]; tg += p[1]; tb += p[2];
                }
            r = fmaf(tr, ww[ty][tx], r);
            g = fmaf(tg, ww[ty][tx], g);
            b = fmaf(tb, ww[ty][tx], b);
        }
}

// Near-never path (lod > 6, P ~ 1e-7): levels 7..8 on the fly from stored L6.
__device__ float4 read_l6(const char* __restrict__ wsb, int xx, int yy) {
    return dec4(*(const unsigned*)(wsb + OFF6 + ((((size_t)yy << 6) + xx) << 2)));
}

__device__ void sample_coarse(const char* __restrict__ wsb, int lvl,
                              float u, float v, float wgt,
                              float& r, float& g, float& b) {
    int size = 4096 >> lvl;          // 32 (l=7) or 16 (l=8)
    float fs = (float)size;
    float x = u * fs - 0.5f;
    float y = v * fs - 0.5f;
    float x0f = floorf(x);
    float y0f = floorf(y);
    float fx = x - x0f;
    float fy = y - y0f;
    int m = size - 1;
    int x0 = ((int)x0f) & m;
    int y0 = ((int)y0f) & m;
    int x1 = (x0 + 1) & m;
    int y1 = (y0 + 1) & m;
    int s = lvl - 6;
    int k = 1 << s;
    float inv = wgt / (float)(k * k);
    float ww[2][2] = {{(1.0f - fx) * (1.0f - fy) * inv, fx * (1.0f - fy) * inv},
                      {(1.0f - fx) * fy * inv, fx * fy * inv}};
    int xs[2] = {x0 << s, x1 << s};
    int ys[2] = {y0 << s, y1 << s};
    for (int ty = 0; ty < 2; ++ty)
        for (int tx = 0; tx < 2; ++tx) {
            float tr = 0.0f, tg = 0.0f, tb = 0.0f;
            for (int dy = 0; dy < k; ++dy)
                for (int dx = 0; dx < k; ++dx) {
                    float4 c = read_l6(wsb, xs[tx] + dx, ys[ty] + dy);
                    tr += c.x; tg += c.y; tb += c.z;
                }
            r = fmaf(tr, ww[ty][tx], r);
            g = fmaf(tg, ww[ty][tx], g);
            b = fmaf(tb, ww[ty][tx], b);
        }
}

__device__ __forceinline__ void sample_any(const float* __restrict__ data,
                                           const char* __restrict__ wsb, int lvl,
                                           float u, float v, float wgt,
                                           float& r, float& g, float& b) {
    if (lvl >= 2) {
        if (lvl <= 6) sample_packed(wsb, lvl, u, v, wgt, r, g, b);
        else sample_coarse(wsb, lvl, u, v, wgt, r, g, b);            // ~never
    } else {
        sample_fine(data, lvl, u, v, wgt, r, g, b);                  // rare
    }
}

__global__ __launch_bounds__(256) void vt_sample(const float* __restrict__ data,
                                                 const char* __restrict__ wsb,
                                                 const float* __restrict__ texc,
                                                 const float* __restrict__ deriv,
                                                 float* __restrict__ out) {
    int p = blockIdx.x * 256 + threadIdx.x;

    float2 uv = ((const float2*)texc)[p];
    float4 dv = ((const float4*)deriv)[p];
    float dudx = dv.x * 4096.0f;
    float dvdx = dv.y * 4096.0f;
    float dudy = dv.z * 4096.0f;
    float dvdy = dv.w * 4096.0f;
    float rho2 = fmaxf(fmaf(dudx, dudx, dvdx * dvdx), fmaf(dudy, dudy, dvdy * dvdy));
    float lod = 0.5f * __log2f(fmaxf(rho2, 1e-20f));
    lod = fminf(fmaxf(lod, 0.0f), 8.0f);

    int l0 = (int)lod;            // trunc == floor for lod >= 0
    float f = lod - (float)l0;
    int l1 = (l0 < 8) ? (l0 + 1) : 8;

    float r = 0.0f, g = 0.0f, b = 0.0f;

    if (__builtin_expect((unsigned)(l0 - 2) <= 3u, 1)) {
        // Fused fast path: l0 in [2,5] -> both levels packed. Compute all 8
        // tap offsets, issue all 8 loads, THEN do the weight math (one wait).
        unsigned a00, a01, a10, a11, b00, b01, b10, b11;
        float fx0, fy0, fx1, fy1;
        const char* B0 = wsb + mip_off_b(l0);
        const char* B1 = wsb + mip_off_b(l1);
        tap_off(l0, uv.x, uv.y, a00, a01, a10, a11, fx0, fy0);
        tap_off(l1, uv.x, uv.y, b00, b01, b10, b11, fx1, fy1);
        unsigned q0 = *(const unsigned*)(B0 + a00);
        unsigned q1 = *(const unsigned*)(B0 + a01);
        unsigned q2 = *(const unsigned*)(B0 + a10);
        unsigned q3 = *(const unsigned*)(B0 + a11);
        unsigned q4 = *(const unsigned*)(B1 + b00);
        unsigned q5 = *(const unsigned*)(B1 + b01);
        unsigned q6 = *(const unsigned*)(B1 + b10);
        unsigned q7 = *(const unsigned*)(B1 + b11);
        float w0 = 1.0f - f;
        dec_acc(q0, (1.0f - fx0) * (1.0f - fy0) * w0, r, g, b);
        dec_acc(q1, fx0 * (1.0f - fy0) * w0, r, g, b);
        dec_acc(q2, (1.0f - fx0) * fy0 * w0, r, g, b);
        dec_acc(q3, fx0 * fy0 * w0, r, g, b);
        dec_acc(q4, (1.0f - fx1) * (1.0f - fy1) * f, r, g, b);
        dec_acc(q5, fx1 * (1.0f - fy1) * f, r, g, b);
        dec_acc(q6, (1.0f - fx1) * fy1 * f, r, g, b);
        dec_acc(q7, fx1 * fy1 * f, r, g, b);
    } else {
        sample_any(data, wsb, l0, uv.x, uv.y, 1.0f - f, r, g, b);
        sample_any(data, wsb, l1, uv.x, uv.y, f, r, g, b);
    }

    float* o = out + (size_t)p * 3;
    o[0] = r;
    o[1] = g;
    o[2] = b;
}

extern "C" void kernel_launch(void* const* d_in, const int* in_sizes, int n_in,
                              void* d_out, int out_size, void* d_ws, size_t ws_size,
                              hipStream_t stream) {
    const float* data  = (const float*)d_in[0];
    const float* texc  = (const float*)d_in[1];
    const float* deriv = (const float*)d_in[2];
    float* out = (float*)d_out;
    char* wsb  = (char*)d_ws;

    mip_l2<<<256, 256, 0, stream>>>(data, wsb);
    mip_rest<<<1024, 256, 0, stream>>>(wsb);
    vt_sample<<<OUT_N / 256, 256, 0, stream>>>(data, wsb, texc, deriv, out);
}

// Round 8
// 327.176 us; speedup vs baseline: 1.0429x; 1.0429x over previous
//
#include <hip/hip_runtime.h>
#include <hip/hip_bf16.h>

// VirtualTextureModule: trilinear mip-mapped texture sampling.
// data [1,4096,4096,3] f32, texc [1,1024,1024,2] f32, texc_deriv [1,1024,1024,4] f32
// out  [1,1024,1024,3] f32
//
// R11.1 = R11 resubmit (previous round failed on GPU acquisition, not kernel).
// R11 = revert to R7 (best measured: 326.8 us; R5-class 325.7 within noise).
// Rationale: six structurally independent mip-builder designs (LDS ladder,
// gload_lds dense 768B/12KB runs, register sparse/dense, persistent counted-
// vmcnt pipeline) all pin the 201-MB cold read at 2.4-2.9 TB/s; no lever
// moved it. This is the best-measured configuration; mip ~81 us, sampler
// ~8 us, harness fills ~235 us of the timed region.
//
//  - mip_fused: one block = 64x64 input tile (4096 blocks), staged to LDS
//    with float4-LINEAR global_load_lds w=16 (dense 1-KB wave transactions,
//    no over-fetch). 256 threads compute one L2 texel each (4x4 raw box);
//    L3/L4/L5/L6 fold into the quad-store ladder. s3/s4/s5 alias the dead
//    raw buffer: LDS = 52.3 KB -> 3 blocks/CU.
//  - sampler: fused dual-level fast path for l0 in [2,5] (~98.6%): all 8 tap
//    offsets computed, 8 loads issued back-to-back, one wait. Rare fine
//    (lod<2, from data) and coarse (lod>6, from stored L6) fallbacks.
//  - storage: mips 2..6 as u32 RGB 10:10:10, 2x2-quad tiled (quad = 16 B).

#define OUT_N (1024 * 1024)

__device__ __forceinline__ unsigned mip_off_b(int lvl) {
    return (67108864u - (67108864u >> (2 * lvl - 2))) / 3u;
}
#define OFF2 16777216u
#define OFF3 20971520u
#define OFF4 22020096u
#define OFF5 22282240u
#define OFF6 22347776u

__device__ __forceinline__ unsigned pack10(float r, float g, float b) {
    unsigned ur = __float2uint_rn(r * 1023.0f);
    unsigned ug = __float2uint_rn(g * 1023.0f);
    unsigned ub = __float2uint_rn(b * 1023.0f);
    return ur | (ug << 10) | (ub << 20);
}

__device__ __forceinline__ void dec_acc(unsigned q, float w, float& r, float& g, float& b) {
    const float s = 1.0f / 1023.0f;
    r = fmaf((float)(q & 1023u) * s, w, r);
    g = fmaf((float)((q >> 10) & 1023u) * s, w, g);
    b = fmaf((float)((q >> 20) & 1023u) * s, w, b);
}

__device__ __forceinline__ float4 dec4(unsigned q) {
    const float s = 1.0f / 1023.0f;
    return float4{(float)(q & 1023u) * s, (float)((q >> 10) & 1023u) * s,
                  (float)((q >> 20) & 1023u) * s, 0.0f};
}

__device__ __forceinline__ float4 avg4(float4 a, float4 b, float4 c, float4 d) {
    return float4{(a.x + b.x + c.x + d.x) * 0.25f,
                  (a.y + b.y + c.y + d.y) * 0.25f,
                  (a.z + b.z + c.z + d.z) * 0.25f, 0.0f};
}

__device__ __forceinline__ void store_quad(char* p, float4 t00, float4 t01,
                                           float4 t10, float4 t11) {
    *(uint4*)p = make_uint4(pack10(t00.x, t00.y, t00.z), pack10(t01.x, t01.y, t01.z),
                            pack10(t10.x, t10.y, t10.z), pack10(t11.x, t11.y, t11.z));
}

// ---------------- mip build: one block = 64x64 input tile, 4096 blocks ----
// LDS pool layout:
//   [0, 49152)        raw tile, 64 rows x 768 B (float4-linear)   [phases 0-1]
//   [0, 1152)         s3: 8x9 float4 (L3 texels)                  [phase 2+, aliases raw]
//   [2048, 2368)      s4: 4x5 float4 (L4 texels)
//   [4096, 4192)      s5: 2x3 float4 (L5 texels)
//   [49152, 53504)    s2: 16x17 float4 (L2 texels)
#define POOL_BYTES (49152 + 4352)

__global__ __launch_bounds__(256) void mip_fused(const float* __restrict__ data,
                                                 char* __restrict__ wsb) {
    __shared__ float4 pool4[POOL_BYTES / 16];
    char* pool = (char*)pool4;
    float4(*s2)[17] = (float4(*)[17])(pool + 49152);
    float4(*s3)[9]  = (float4(*)[9])(pool + 0);
    float4(*s4)[5]  = (float4(*)[5])(pool + 2048);
    float4(*s5)[3]  = (float4(*)[3])(pool + 4096);

    const int t = threadIdx.x;
    const int bx = blockIdx.x & 63;      // 64 tiles per row
    const int by = blockIdx.x >> 6;

    // ---- phase 0: linear copy of the 64x64 tile into LDS ----
    // Tile row r (64 rows) = 768 B at data_byte + r*49152, 16-B aligned.
    {
        const char* src = (const char*)data + (size_t)by * 64 * 49152 + (size_t)bx * 768;
#pragma unroll
        for (int j = 0; j < 12; ++j) {
            int f = t + j * 256;            // float4 index in [0, 3072)
            int row = f / 48;               // 48 float4 per tile row
            int col = f - row * 48;
            const char* g = src + (size_t)row * 49152 + (size_t)col * 16;
            __builtin_amdgcn_global_load_lds(
                (const __attribute__((address_space(1))) unsigned int*)g,
                (__attribute__((address_space(3))) unsigned int*)(pool + (size_t)f * 16),
                16, 0, 0);
        }
    }
    __syncthreads();

    // ---- phase 1: every thread computes one L2 texel (4x4 raw box) ----
    {
        int tx = t & 15, ty = t >> 4;
        float rr = 0.0f, gg = 0.0f, bb = 0.0f;
#pragma unroll
        for (int i = 0; i < 4; ++i) {
            const float4* rp = (const float4*)(pool + (size_t)(4 * ty + i) * 768 + (size_t)tx * 48);
            float4 A = rp[0], Bv = rp[1], Cv = rp[2];
            // texels: (A.x,A.y,A.z)(A.w,Bv.x,Bv.y)(Bv.z,Bv.w,Cv.x)(Cv.y,Cv.z,Cv.w)
            rr += A.x + A.w + Bv.z + Cv.y;
            gg += A.y + Bv.x + Bv.w + Cv.z;
            bb += A.z + Bv.y + Cv.x + Cv.w;
        }
        const float sc = 1.0f / 16.0f;
        float4 tex = {rr * sc, gg * sc, bb * sc, 0.0f};
        __syncthreads();                 // raw reads done before s2/s3 alias writes
        s2[ty][tx] = tex;
    }
    __syncthreads();

    // ---- phase 2: t<64: store L2 quad + produce L3 texel ----
    if (t < 64) {
        int qx = t & 7, qy = t >> 3;
        float4 t00 = s2[2 * qy][2 * qx],     t01 = s2[2 * qy][2 * qx + 1];
        float4 t10 = s2[2 * qy + 1][2 * qx], t11 = s2[2 * qy + 1][2 * qx + 1];
        unsigned gq = ((by << 3) + qy) * 512u + (bx << 3) + qx;
        store_quad(wsb + OFF2 + ((size_t)gq << 4), t00, t01, t10, t11);
        s3[qy][qx] = avg4(t00, t01, t10, t11);
    }
    __syncthreads();

    // ---- phase 3: t<16: store L3 quad + produce L4 texel ----
    if (t < 16) {
        int qx = t & 3, qy = t >> 2;
        float4 t00 = s3[2 * qy][2 * qx],     t01 = s3[2 * qy][2 * qx + 1];
        float4 t10 = s3[2 * qy + 1][2 * qx], t11 = s3[2 * qy + 1][2 * qx + 1];
        unsigned gq = ((by << 2) + qy) * 256u + (bx << 2) + qx;
        store_quad(wsb + OFF3 + ((size_t)gq << 4), t00, t01, t10, t11);
        s4[qy][qx] = avg4(t00, t01, t10, t11);
    }
    __syncthreads();

    // ---- phase 4: t<4: store L4 quad + produce L5 texel ----
    if (t < 4) {
        int qx = t & 1, qy = t >> 1;
        float4 t00 = s4[2 * qy][2 * qx],     t01 = s4[2 * qy][2 * qx + 1];
        float4 t10 = s4[2 * qy + 1][2 * qx], t11 = s4[2 * qy + 1][2 * qx + 1];
        unsigned gq = ((by << 1) + qy) * 128u + (bx << 1) + qx;
        store_quad(wsb + OFF4 + ((size_t)gq << 4), t00, t01, t10, t11);
        s5[qy][qx] = avg4(t00, t01, t10, t11);
    }
    __syncthreads();

    // ---- phase 5: t==0: store L5 quad + packed L6 texel ----
    if (t == 0) {
        float4 t00 = s5[0][0], t01 = s5[0][1], t10 = s5[1][0], t11 = s5[1][1];
        unsigned gq = (unsigned)by * 64u + (unsigned)bx;      // 64 quads/row
        store_quad(wsb + OFF5 + ((size_t)gq << 4), t00, t01, t10, t11);
        float4 l6 = avg4(t00, t01, t10, t11);
        size_t a6 = OFF6 + ((((by >> 1) * 32) + (bx >> 1)) << 4) +
                    ((by & 1) << 3) + ((bx & 1) << 2);
        *(unsigned*)(wsb + a6) = pack10(l6.x, l6.y, l6.z);
    }
}

// ---------------- sampling ----------------
__device__ __forceinline__ void tap_off(int lvl, float u, float v,
                                        unsigned& o00, unsigned& o01,
                                        unsigned& o10, unsigned& o11,
                                        float& fx, float& fy) {
    int size = 4096 >> lvl;
    float fs = (float)size;
    float x = fmaf(u, fs, -0.5f);
    float y = fmaf(v, fs, -0.5f);
    float x0f = floorf(x);
    float y0f = floorf(y);
    fx = x - x0f;
    fy = y - y0f;
    int m = size - 1;
    int x0 = ((int)x0f) & m;
    int y0 = ((int)y0f) & m;
    int x1 = (x0 + 1) & m;
    int y1 = (y0 + 1) & m;
    int hs = size >> 1;
    unsigned r0 = (unsigned)((y0 >> 1) * hs);
    unsigned r1 = (unsigned)((y1 >> 1) * hs);
    unsigned c0 = (unsigned)(x0 >> 1), c1 = (unsigned)(x1 >> 1);
    unsigned sy0 = (unsigned)((y0 & 1) << 3), sy1 = (unsigned)((y1 & 1) << 3);
    unsigned sx0 = (unsigned)((x0 & 1) << 2), sx1 = (unsigned)((x1 & 1) << 2);
    o00 = ((r0 + c0) << 4) + sy0 + sx0;
    o01 = ((r0 + c1) << 4) + sy0 + sx1;
    o10 = ((r1 + c0) << 4) + sy1 + sx0;
    o11 = ((r1 + c1) << 4) + sy1 + sx1;
}

__device__ __forceinline__ void sample_packed(const char* __restrict__ wsb, int lvl,
                                              float u, float v, float wgt,
                                              float& r, float& g, float& b) {
    unsigned o00, o01, o10, o11;
    float fx, fy;
    tap_off(lvl, u, v, o00, o01, o10, o11, fx, fy);
    const char* B = wsb + mip_off_b(lvl);
    unsigned q00 = *(const unsigned*)(B + o00);
    unsigned q01 = *(const unsigned*)(B + o01);
    unsigned q10 = *(const unsigned*)(B + o10);
    unsigned q11 = *(const unsigned*)(B + o11);
    dec_acc(q00, (1.0f - fx) * (1.0f - fy) * wgt, r, g, b);
    dec_acc(q01, fx * (1.0f - fy) * wgt, r, g, b);
    dec_acc(q10, (1.0f - fx) * fy * wgt, r, g, b);
    dec_acc(q11, fx * fy * wgt, r, g, b);
}

// Rare path (lod < 2, ~1.3%): levels 0..1 on the fly from fp32 data.
__device__ void sample_fine(const float* __restrict__ data, int lvl,
                            float u, float v, float wgt,
                            float& r, float& g, float& b) {
    int size = 4096 >> lvl;
    float fs = (float)size;
    float x = u * fs - 0.5f;
    float y = v * fs - 0.5f;
    float x0f = floorf(x);
    float y0f = floorf(y);
    float fx = x - x0f;
    float fy = y - y0f;
    int m = size - 1;
    int x0 = ((int)x0f) & m;
    int y0 = ((int)y0f) & m;
    int x1 = (x0 + 1) & m;
    int y1 = (y0 + 1) & m;
    int k = 1 << lvl;
    float inv = wgt / (float)(k * k);
    float ww[2][2] = {{(1.0f - fx) * (1.0f - fy) * inv, fx * (1.0f - fy) * inv},
                      {(1.0f - fx) * fy * inv, fx * fy * inv}};
    int xs[2] = {x0 << lvl, x1 << lvl};
    int ys[2] = {y0 << lvl, y1 << lvl};
    for (int ty = 0; ty < 2; ++ty)
        for (int tx = 0; tx < 2; ++tx) {
            float tr = 0.0f, tg = 0.0f, tb = 0.0f;
            for (int dy = 0; dy < k; ++dy)
                for (int dx = 0; dx < k; ++dx) {
                    const float* p = data + ((size_t)(ys[ty] + dy) * 4096 + xs[tx] + dx) * 3;
                    tr += p[0]; tg += p[1]; tb += p[2];
                }
            r = fmaf(tr, ww[ty][tx], r);
            g = fmaf(tg, ww[ty][tx], g);
            b = fmaf(tb, ww[ty][tx], b);
        }
}

// Near-never path (lod > 6, P ~ 1e-7): levels 7..8 on the fly from stored L6.
__device__ float4 read_l6(const char* __restrict__ wsb, int xx, int yy) {
    size_t a = OFF6 + ((((yy >> 1) * 32) + (xx >> 1)) << 4) + ((yy & 1) << 3) + ((xx & 1) << 2);
    return dec4(*(const unsigned*)(wsb + a));
}

__device__ void sample_coarse(const char* __restrict__ wsb, int lvl,
                              float u, float v, float wgt,
                              float& r, float& g, float& b) {
    int size = 4096 >> lvl;          // 32 (l=7) or 16 (l=8)
    float fs = (float)size;
    float x = u * fs - 0.5f;
    float y = v * fs - 0.5f;
    float x0f = floorf(x);
    float y0f = floorf(y);
    float fx = x - x0f;
    float fy = y - y0f;
    int m = size - 1;
    int x0 = ((int)x0f) & m;
    int y0 = ((int)y0f) & m;
    int x1 = (x0 + 1) & m;
    int y1 = (y0 + 1) & m;
    int s = lvl - 6;
    int k = 1 << s;
    float inv = wgt / (float)(k * k);
    float ww[2][2] = {{(1.0f - fx) * (1.0f - fy) * inv, fx * (1.0f - fy) * inv},
                      {(1.0f - fx) * fy * inv, fx * fy * inv}};
    int xs[2] = {x0 << s, x1 << s};
    int ys[2] = {y0 << s, y1 << s};
    for (int ty = 0; ty < 2; ++ty)
        for (int tx = 0; tx < 2; ++tx) {
            float tr = 0.0f, tg = 0.0f, tb = 0.0f;
            for (int dy = 0; dy < k; ++dy)
                for (int dx = 0; dx < k; ++dx) {
                    float4 c = read_l6(wsb, xs[tx] + dx, ys[ty] + dy);
                    tr += c.x; tg += c.y; tb += c.z;
                }
            r = fmaf(tr, ww[ty][tx], r);
            g = fmaf(tg, ww[ty][tx], g);
            b = fmaf(tb, ww[ty][tx], b);
        }
}

__device__ __forceinline__ void sample_any(const float* __restrict__ data,
                                           const char* __restrict__ wsb, int lvl,
                                           float u, float v, float wgt,
                                           float& r, float& g, float& b) {
    if (lvl >= 2) {
        if (lvl <= 6) sample_packed(wsb, lvl, u, v, wgt, r, g, b);
        else sample_coarse(wsb, lvl, u, v, wgt, r, g, b);            // ~never
    } else {
        sample_fine(data, lvl, u, v, wgt, r, g, b);                  // rare
    }
}

__global__ __launch_bounds__(256) void vt_sample(const float* __restrict__ data,
                                                 const char* __restrict__ wsb,
                                                 const float* __restrict__ texc,
                                                 const float* __restrict__ deriv,
                                                 float* __restrict__ out) {
    int p = blockIdx.x * 256 + threadIdx.x;

    float2 uv = ((const float2*)texc)[p];
    float4 dv = ((const float4*)deriv)[p];
    float dudx = dv.x * 4096.0f;
    float dvdx = dv.y * 4096.0f;
    float dudy = dv.z * 4096.0f;
    float dvdy = dv.w * 4096.0f;
    float rho2 = fmaxf(fmaf(dudx, dudx, dvdx * dvdx), fmaf(dudy, dudy, dvdy * dvdy));
    float lod = 0.5f * __log2f(fmaxf(rho2, 1e-20f));
    lod = fminf(fmaxf(lod, 0.0f), 8.0f);

    int l0 = (int)lod;            // trunc == floor for lod >= 0
    float f = lod - (float)l0;
    int l1 = (l0 < 8) ? (l0 + 1) : 8;

    float r = 0.0f, g = 0.0f, b = 0.0f;

    if (__builtin_expect((unsigned)(l0 - 2) <= 3u, 1)) {
        // Fused fast path: l0 in [2,5] -> both levels packed. Compute all 8
        // tap offsets, issue all 8 loads, THEN do the weight math (one wait).
        unsigned a00, a01, a10, a11, b00, b01, b10, b11;
        float fx0, fy0, fx1, fy1;
        const char* B0 = wsb + mip_off_b(l0);
        const char* B1 = wsb + mip_off_b(l1);
        tap_off(l0, uv.x, uv.y, a00, a01, a10, a11, fx0, fy0);
        tap_off(l1, uv.x, uv.y, b00, b01, b10, b11, fx1, fy1);
        unsigned q0 = *(const unsigned*)(B0 + a00);
        unsigned q1 = *(const unsigned*)(B0 + a01);
        unsigned q2 = *(const unsigned*)(B0 + a10);
        unsigned q3 = *(const unsigned*)(B0 + a11);
        unsigned q4 = *(const unsigned*)(B1 + b00);
        unsigned q5 = *(const unsigned*)(B1 + b01);
        unsigned q6 = *(const unsigned*)(B1 + b10);
        unsigned q7 = *(const unsigned*)(B1 + b11);
        float w0 = 1.0f - f;
        dec_acc(q0, (1.0f - fx0) * (1.0f - fy0) * w0, r, g, b);
        dec_acc(q1, fx0 * (1.0f - fy0) * w0, r, g, b);
        dec_acc(q2, (1.0f - fx0) * fy0 * w0, r, g, b);
        dec_acc(q3, fx0 * fy0 * w0, r, g, b);
        dec_acc(q4, (1.0f - fx1) * (1.0f - fy1) * f, r, g, b);
        dec_acc(q5, fx1 * (1.0f - fy1) * f, r, g, b);
        dec_acc(q6, (1.0f - fx1) * fy1 * f, r, g, b);
        dec_acc(q7, fx1 * fy1 * f, r, g, b);
    } else {
        sample_any(data, wsb, l0, uv.x, uv.y, 1.0f - f, r, g, b);
        sample_any(data, wsb, l1, uv.x, uv.y, f, r, g, b);
    }

    float* o = out + (size_t)p * 3;
    o[0] = r;
    o[1] = g;
    o[2] = b;
}

extern "C" void kernel_launch(void* const* d_in, const int* in_sizes, int n_in,
                              void* d_out, int out_size, void* d_ws, size_t ws_size,
                              hipStream_t stream) {
    const float* data  = (const float*)d_in[0];
    const float* texc  = (const float*)d_in[1];
    const float* deriv = (const float*)d_in[2];
    float* out = (float*)d_out;
    char* wsb  = (char*)d_ws;

    mip_fused<<<4096, 256, 0, stream>>>(data, wsb);
    vt_sample<<<OUT_N / 256, 256, 0, stream>>>(data, wsb, texc, deriv, out);
}